// Round 16
// baseline (73.533 us; speedup 1.0000x reference)
//
#include <hip/hip_runtime.h>
#include <cstddef>

#define EPS1f 1e-6f
#define WDf   1e-5f

constexpr int Bsz = 512, Csz = 500, Zsz = 64, Ssz = 100;

typedef short bf16x8 __attribute__((ext_vector_type(8)));
typedef float f32x4 __attribute__((ext_vector_type(4)));

__device__ inline short f2bf(float f) {
  union { float f; unsigned u; } v; v.f = f;
  unsigned r = (v.u + 0x7fffu + ((v.u >> 16) & 1u)) >> 16;   // RNE
  return (short)r;
}

__device__ inline float block_reduce_sum(float v, float* red) {
  #pragma unroll
  for (int off = 32; off > 0; off >>= 1) v += __shfl_down(v, off, 64);
  const int lane = threadIdx.x & 63, wid = threadIdx.x >> 6;
  if (lane == 0) red[wid] = v;
  __syncthreads();
  float r = 0.f;
  if (threadIdx.x == 0) {
    const int nw = blockDim.x >> 6;
    for (int i = 0; i < nw; ++i) r += red[i];
  }
  __syncthreads();
  return r;   // valid in thread 0 only
}

// ---------------- 32x32 double-buffered GEMM body ----------------
__device__ __forceinline__ void gemm32_body(
    const float* __restrict__ A, const float* __restrict__ W,
    const float* __restrict__ bias, float* __restrict__ out,
    int M, int N, int K, int bn0, int bm0, float* As_, float* Ws_, bool relu) {
  const int tid = threadIdx.x;
  const int bn = bn0 * 32, bm = bm0 * 32;
  const int sm = tid >> 3, sk4 = (tid & 7) * 4;
  const int sk = tid >> 3, sn4 = (tid & 7) * 4;
  const int tn = tid & 15, tm = tid >> 4;
  #define AS_(b, k, m) As_[(b) * 1152 + (k) * 36 + (m)]
  #define WS_(b, k, n) Ws_[(b) * 1152 + (k) * 36 + (n)]
  auto loadW = [&](int kt, float4& wv) {
    const float* wrow = W + (size_t)(kt + sk) * N;
    const int nn = bn + sn4;
    if (nn + 3 < N) wv = *reinterpret_cast<const float4*>(wrow + nn);
    else {
      wv.x = (nn + 0 < N) ? wrow[nn + 0] : 0.f;
      wv.y = (nn + 1 < N) ? wrow[nn + 1] : 0.f;
      wv.z = (nn + 2 < N) ? wrow[nn + 2] : 0.f;
      wv.w = (nn + 3 < N) ? wrow[nn + 3] : 0.f;
    }
  };
  {
    float4 av = *reinterpret_cast<const float4*>(A + (size_t)(bm + sm) * K + sk4);
    float4 wv; loadW(0, wv);
    AS_(0, sk4 + 0, sm) = av.x; AS_(0, sk4 + 1, sm) = av.y;
    AS_(0, sk4 + 2, sm) = av.z; AS_(0, sk4 + 3, sm) = av.w;
    *reinterpret_cast<float4*>(&WS_(0, sk, sn4)) = wv;
  }
  __syncthreads();
  float acc[2][2] = {};
  int pb = 0;
  for (int kt = 0; kt < K; kt += 32) {
    const bool more = (kt + 32) < K;
    float4 av2, wv2;
    if (more) {
      av2 = *reinterpret_cast<const float4*>(A + (size_t)(bm + sm) * K + kt + 32 + sk4);
      loadW(kt + 32, wv2);
    }
    #pragma unroll
    for (int k = 0; k < 32; ++k) {
      const float2 a = *reinterpret_cast<const float2*>(&AS_(pb, k, tm * 2));
      const float2 w = *reinterpret_cast<const float2*>(&WS_(pb, k, tn * 2));
      acc[0][0] = fmaf(a.x, w.x, acc[0][0]);
      acc[0][1] = fmaf(a.x, w.y, acc[0][1]);
      acc[1][0] = fmaf(a.y, w.x, acc[1][0]);
      acc[1][1] = fmaf(a.y, w.y, acc[1][1]);
    }
    if (more) {
      const int nb = pb ^ 1;
      AS_(nb, sk4 + 0, sm) = av2.x; AS_(nb, sk4 + 1, sm) = av2.y;
      AS_(nb, sk4 + 2, sm) = av2.z; AS_(nb, sk4 + 3, sm) = av2.w;
      *reinterpret_cast<float4*>(&WS_(nb, sk, sn4)) = wv2;
      __syncthreads();
      pb = nb;
    }
  }
  #pragma unroll
  for (int j = 0; j < 2; ++j) {
    const int n = bn + tn * 2 + j;
    if (n >= N) continue;
    const float bv = bias[n];
    #pragma unroll
    for (int i = 0; i < 2; ++i) {
      const int m = bm + tm * 2 + i;
      float v = acc[i][j] + bv;
      if (relu) v = fmaxf(v, 0.f);
      out[(size_t)m * N + n] = v;
    }
  }
  #undef AS_
  #undef WS_
}

// ---------------- PREP: nprep(0-799) | sqrtcov(800-807) | RbF(808-823) | l2(824-887)
// | gemm1(888-951) | padinit(952-983) ----------------
__global__ __launch_bounds__(256) void prep_kernel(
    const float* __restrict__ noise, short* __restrict__ nfB,
    const float* __restrict__ R, short* __restrict__ RbF, float* __restrict__ sqrtcov,
    const float* __restrict__ X, const float* __restrict__ W1,
    const float* __restrict__ b1, float* __restrict__ h1,
    const float* __restrict__ W2, const float* __restrict__ W3,
    const float* __restrict__ Wmu, float* __restrict__ l2_part,
    unsigned* __restrict__ rsPu) {
  __shared__ float smem[2304 * 2];
  const int blk = blockIdx.x;
  const int tid = threadIdx.x;
  if (blk < 800) {
    // noise -> bf16 MFMA-fragment layout
    const int g = blk * 256 + tid;       // 204800
    const int s = g >> 11;
    const int r = g & 2047;
    const int bt = r >> 6;
    const int ln = r & 63;
    const int cl = ln & 15, grp = ln >> 4;
    const float* src = noise + ((size_t)(s * 512 + bt * 16 + cl) * 64 + grp * 8);
    const float4 a = *reinterpret_cast<const float4*>(src);
    const float4 b = *reinterpret_cast<const float4*>(src + 4);
    const float4 c = *reinterpret_cast<const float4*>(src + 32);
    const float4 d = *reinterpret_cast<const float4*>(src + 36);
    bf16x8* dst = reinterpret_cast<bf16x8*>(nfB);
    const int u = (s * 32 + bt) * 128 + ln;
    dst[u]      = bf16x8{ f2bf(a.x), f2bf(a.y), f2bf(a.z), f2bf(a.w),
                          f2bf(b.x), f2bf(b.y), f2bf(b.z), f2bf(b.w) };
    dst[u + 64] = bf16x8{ f2bf(c.x), f2bf(c.y), f2bf(c.z), f2bf(c.w),
                          f2bf(d.x), f2bf(d.y), f2bf(d.z), f2bf(d.w) };
  } else if (blk < 808) {
    // sqrt(cov_diag): 4 threads per c
    const int idx = (blk - 800) * 256 + tid;   // 0..2047
    const int c = idx >> 2;
    const int zq = (idx & 3) * 16;
    const bool cv = c < Csz;
    const float* src = R + (size_t)c * Zsz + zq;
    float ss = 0.f;
    if (cv) {
      #pragma unroll
      for (int q = 0; q < 4; ++q) {
        const float4 r4 = *reinterpret_cast<const float4*>(src + q * 4);
        ss = fmaf(r4.x, r4.x, ss); ss = fmaf(r4.y, r4.y, ss);
        ss = fmaf(r4.z, r4.z, ss); ss = fmaf(r4.w, r4.w, ss);
      }
    }
    ss += __shfl_xor(ss, 1, 64);
    ss += __shfl_xor(ss, 2, 64);
    if ((idx & 3) == 0 && cv) sqrtcov[c] = sqrtf(1.f + ss);
  } else if (blk < 824) {
    // R -> bf16 MFMA-fragment layout (zero-padded rows >= Csz)
    const int e = (blk - 808) * 256 + tid;     // 0..4095
    const int ct = e >> 7;
    const int f = (e >> 6) & 1;
    const int lane = e & 63;
    const int cl = lane & 15, grp = lane >> 4;
    const int c = ct * 16 + cl;
    bf16x8 out = {0, 0, 0, 0, 0, 0, 0, 0};
    if (c < Csz) {
      const float* src = R + (size_t)c * Zsz + f * 32 + grp * 8;
      const float4 a = *reinterpret_cast<const float4*>(src);
      const float4 b = *reinterpret_cast<const float4*>(src + 4);
      out = bf16x8{ f2bf(a.x), f2bf(a.y), f2bf(a.z), f2bf(a.w),
                    f2bf(b.x), f2bf(b.y), f2bf(b.z), f2bf(b.w) };
    }
    reinterpret_cast<bf16x8*>(RbF)[e] = out;
  } else if (blk < 888) {
    const int bid = blk - 824;
    const int gid = bid * 256 + tid;
    const int stride = 64 * 256;
    float s = 0.f;
    for (int i = gid; i < 65536; i += stride) { float v = W1[i]; s = fmaf(v, v, s); }
    for (int i = gid; i < 32768; i += stride) { float v = W2[i]; s = fmaf(v, v, s); }
    for (int i = gid; i < 65536; i += stride) { float v = W3[i]; s = fmaf(v, v, s); }
    for (int i = gid; i < 128000; i += stride) { float v = Wmu[i]; s = fmaf(v, v, s); }
    const float tot = block_reduce_sum(s, smem);
    if (tid == 0) l2_part[bid] = tot;
  } else if (blk < 952) {
    const int idx = blk - 888;                  // 0..63
    gemm32_body(X, W1, b1, h1, 512, 128, 512, idx & 3, idx >> 2,
                smem, smem + 2304, true);
  } else {
    // pad-init rsPu for n in [496,512): rs=+0.0 (LSB=0 -> sn=+0.7071), acc=0 -> u=0 -> E=0.5
    const int g = (blk - 952) * 256 + tid;      // 0..8191
    const int m = g >> 4;
    const int n = 496 + (g & 15);
    const int idx = ((n >> 4) * 32 + (m >> 4)) * 256
                  + (((n >> 2) & 3) * 16 + (m & 15)) * 4 + (n & 3);
    rsPu[idx] = 0u;
  }
}

// ---------------- standalone 32x32 GEMM ----------------
template <bool RELU>
__global__ __launch_bounds__(256) void gemm32(
    const float* __restrict__ A, const float* __restrict__ W,
    const float* __restrict__ bias, float* __restrict__ out,
    int M, int N, int K) {
  __shared__ float smem[2304 * 2];
  gemm32_body(A, W, bias, out, M, N, K, blockIdx.x, blockIdx.y,
              smem, smem + 2304, RELU);
}

// ---------------- MU GEMM: -> indiv_prob, CE partials, LSB-encoded rsPu ----------------
// rs = rmu*snc (f32); LSB of mantissa = y (1 -> snc negative). 1-ulp perturbation only.
__global__ __launch_bounds__(256) void gemm32_mu(
    const float* __restrict__ A, const float* __restrict__ W,
    const float* __restrict__ bias, const float* __restrict__ Y,
    const float* __restrict__ sqrtcov,
    float* __restrict__ out_prob, unsigned* __restrict__ rsPu,
    float* __restrict__ ce_part, int M, int N, int K) {
  __shared__ float As[2][32][36];
  __shared__ float Ws[2][32][36];
  const int tid = threadIdx.x;
  const int bn = blockIdx.x * 32, bm = blockIdx.y * 32;
  const int sm = tid >> 3, sk4 = (tid & 7) * 4;
  const int sk = tid >> 3, sn4 = (tid & 7) * 4;
  const int tn = tid & 15, tm = tid >> 4;

  auto loadW = [&](int kt, float4& wv) {
    const float* wrow = W + (size_t)(kt + sk) * N;
    const int nn = bn + sn4;
    if (nn + 3 < N) wv = *reinterpret_cast<const float4*>(wrow + nn);
    else {
      wv.x = (nn + 0 < N) ? wrow[nn + 0] : 0.f;
      wv.y = (nn + 1 < N) ? wrow[nn + 1] : 0.f;
      wv.z = (nn + 2 < N) ? wrow[nn + 2] : 0.f;
      wv.w = (nn + 3 < N) ? wrow[nn + 3] : 0.f;
    }
  };
  {
    float4 av = *reinterpret_cast<const float4*>(A + (size_t)(bm + sm) * K + sk4);
    float4 wv; loadW(0, wv);
    As[0][sk4 + 0][sm] = av.x; As[0][sk4 + 1][sm] = av.y;
    As[0][sk4 + 2][sm] = av.z; As[0][sk4 + 3][sm] = av.w;
    *reinterpret_cast<float4*>(&Ws[0][sk][sn4]) = wv;
  }
  __syncthreads();
  float acc[2][2] = {};
  int pb = 0;
  for (int kt = 0; kt < K; kt += 32) {
    const bool more = (kt + 32) < K;
    float4 av2, wv2;
    if (more) {
      av2 = *reinterpret_cast<const float4*>(A + (size_t)(bm + sm) * K + kt + 32 + sk4);
      loadW(kt + 32, wv2);
    }
    #pragma unroll
    for (int k = 0; k < 32; ++k) {
      const float2 a = *reinterpret_cast<const float2*>(&As[pb][k][tm * 2]);
      const float2 w = *reinterpret_cast<const float2*>(&Ws[pb][k][tn * 2]);
      acc[0][0] = fmaf(a.x, w.x, acc[0][0]);
      acc[0][1] = fmaf(a.x, w.y, acc[0][1]);
      acc[1][0] = fmaf(a.y, w.x, acc[1][0]);
      acc[1][1] = fmaf(a.y, w.y, acc[1][1]);
    }
    if (more) {
      const int nb = pb ^ 1;
      As[nb][sk4 + 0][sm] = av2.x; As[nb][sk4 + 1][sm] = av2.y;
      As[nb][sk4 + 2][sm] = av2.z; As[nb][sk4 + 3][sm] = av2.w;
      *reinterpret_cast<float4*>(&Ws[nb][sk][sn4]) = wv2;
      __syncthreads();
      pb = nb;
    }
  }
  float ce2[2] = {0.f, 0.f};
  #pragma unroll
  for (int i = 0; i < 2; ++i) {
    const int m = bm + tm * 2 + i;
    #pragma unroll
    for (int j = 0; j < 2; ++j) {
      const int n = bn + tn * 2 + j;
      if (n < N) {
        const float v = acc[i][j] + bias[n];
        const float sp = __builtin_amdgcn_rcpf(1.f + __expf(-1.70169f * v));
        const float p = fmaf(sp, 1.f - EPS1f, 0.5f * EPS1f);
        const float q = fmaf(1.f - sp, 1.f - EPS1f, 0.5f * EPS1f);
        const float y = Y[(size_t)m * N + n];
        out_prob[(size_t)m * N + n] = p;
        ce2[i] += __logf((y > 0.5f) ? p : q);
        // fragment-ordered: idx = (ct*32+bt)*256 + lane*4 + j
        const int idx = (((n >> 4) * 32 + (m >> 4)) << 8)
                      + ((((n >> 2) & 3) * 16 + (m & 15)) << 2) + (n & 3);
        const float snc = (y > 0.5f) ? -0.70710678f : 0.70710678f;
        unsigned bits = __float_as_uint(v * sqrtcov[n] * snc);
        bits = (bits & ~1u) | ((y > 0.5f) ? 1u : 0u);
        rsPu[idx] = bits;
      }
    }
  }
  #pragma unroll
  for (int off = 1; off < 16; off <<= 1) {
    ce2[0] += __shfl_xor(ce2[0], off, 64);
    ce2[1] += __shfl_xor(ce2[1], off, 64);
  }
  if (tn == 0) {
    const int m0 = bm + tm * 2;
    ce_part[(size_t)blockIdx.x * Bsz + m0] = ce2[0];
    ce_part[(size_t)blockIdx.x * Bsz + m0 + 1] = ce2[1];
  }
}

// ---------------- HOT: c-inner MFMA + probit, LDS-staged R, single 16B stream ----------------
// grid = 100 s x 8 btg x 4 chq = 3200 blocks; block = 4 waves sharing one chq (bt = btg*4+wid).
// RbF staged in LDS (16 KB, 4-wave reuse); rs+sign in ONE f32 stream (LSB = y).
__global__ void logprob_s4(
    const short* __restrict__ nfB, const short* __restrict__ RbF,
    const unsigned* __restrict__ rsPu, float* __restrict__ lp4) {
  const int blk = blockIdx.x;          // chq + 4*btg + 32*s
  const int chq = blk & 3;
  const int btg = (blk >> 2) & 7;
  const int s = blk >> 5;
  const int wid = threadIdx.x >> 6;
  const int lane = threadIdx.x & 63;
  const int bt = btg * 4 + wid;

  __shared__ short lds[16 * 64 * 8];   // 16 KB: 16 fragment-entries x 64 lanes x 8 bf16
  bf16x8* ldsv = reinterpret_cast<bf16x8*>(lds);
  const bf16x8* rf = reinterpret_cast<const bf16x8*>(RbF);
  #pragma unroll
  for (int e = 0; e < 4; ++e)
    ldsv[(e * 4 + wid) * 64 + lane] = rf[(chq * 16 + e * 4 + wid) * 64 + lane];

  const bf16x8* nf = reinterpret_cast<const bf16x8*>(nfB);
  const int nbase = (s * 32 + bt) * 128 + lane;
  const bf16x8 n0 = nf[nbase];               // resident noise frag
  const bf16x8 n1 = nf[nbase + 64];
  __syncthreads();

  float lpl = 0.f;                           // log2 domain
  #pragma unroll
  for (int t = 0; t < 8; ++t) {
    const int ct = chq * 8 + t;
    const bf16x8 Rf0 = ldsv[(t * 2 + 0) * 64 + lane];
    const bf16x8 Rf1 = ldsv[(t * 2 + 1) * 64 + lane];
    f32x4 acc = {0.f, 0.f, 0.f, 0.f};
    acc = __builtin_amdgcn_mfma_f32_16x16x32_bf16(Rf0, n0, acc, 0, 0, 0);
    acc = __builtin_amdgcn_mfma_f32_16x16x32_bf16(Rf1, n1, acc, 0, 0, 0);
    const uint4 qv = *reinterpret_cast<const uint4*>(rsPu + (ct * 32 + bt) * 256 + lane * 4);
    const unsigned qq[4] = {qv.x, qv.y, qv.z, qv.w};
    float u[4], sc[4], p[4], e[4];
    #pragma unroll
    for (int i = 0; i < 4; ++i) {
      const float rs = __uint_as_float(qq[i]);
      const float sn = __uint_as_float(0x3F3504F3u ^ ((qq[i] & 1u) << 31));
      u[i] = fmaf(acc[i], sn, rs);
    }
    #pragma unroll
    for (int i = 0; i < 4; ++i)
      sc[i] = __builtin_amdgcn_rcpf(fmaf(0.3275911f, fabsf(u[i]), 1.f));
    #pragma unroll
    for (int i = 0; i < 4; ++i) {
      float q = fmaf(0.5307027145f, sc[i], -0.7265760135f);   // halved A&S coeffs
      q = fmaf(q, sc[i], 0.7107068705f);
      q = fmaf(q, sc[i], -0.142248368f);
      q = fmaf(q, sc[i], 0.127414796f);
      p[i] = q * sc[i];                                        // = 0.5*erfc_poly
    }
    #pragma unroll
    for (int i = 0; i < 4; ++i) e[i] = __expf(-u[i] * u[i]);
    #pragma unroll
    for (int i = 0; i < 4; ++i) {
      const float f = p[i] * e[i];                // Phi for u>=0
      const float Phi = (u[i] < 0.f) ? 1.f - f : f;
      lpl += __log2f(fmaf(Phi, 1.f - EPS1f, 0.5f * EPS1f));
    }
  }
  lpl += __shfl_xor(lpl, 16, 64);
  lpl += __shfl_xor(lpl, 32, 64);
  if (lane < 16) {
    // pad c's (500-511, all in chq 3) each contribute exactly -1.0 in log2
    const float fix = (chq == 3) ? 12.0f : 0.f;
    lp4[(size_t)(chq * Ssz + s) * 512 + bt * 16 + lane] =
        (lpl + fix) * 0.69314718055994531f;
  }
}

// ---------------- per-b log-sum-exp over S (4-way s-parallel, 4-chunk fused) ----------------
__global__ __launch_bounds__(256) void nll_kernel(const float* __restrict__ lp4,
                                                  float* __restrict__ nll_b) {
  __shared__ float sm[4][64], sse[4][64];
  const int bl = threadIdx.x & 63;
  const int sc = threadIdx.x >> 6;
  const int b = blockIdx.x * 64 + bl;
  float m = -3.0e38f, se = 0.f;
  for (int s = sc * 25; s < sc * 25 + 25; ++s) {
    const float v = lp4[(size_t)s * 512 + b]
                  + lp4[(size_t)(Ssz + s) * 512 + b]
                  + lp4[(size_t)(2 * Ssz + s) * 512 + b]
                  + lp4[(size_t)(3 * Ssz + s) * 512 + b];
    const float mn = fmaxf(m, v);
    se = se * __expf(m - mn) + __expf(v - mn);
    m = mn;
  }
  sm[sc][bl] = m; sse[sc][bl] = se;
  __syncthreads();
  if (sc == 0) {
    float M = sm[0][bl];
    #pragma unroll
    for (int i = 1; i < 4; ++i) M = fmaxf(M, sm[i][bl]);
    float SE = 0.f;
    #pragma unroll
    for (int i = 0; i < 4; ++i) SE += sse[i][bl] * __expf(sm[i][bl] - M);
    nll_b[b] = -__logf(SE * (1.f / (float)Ssz)) - M;
  }
}

// ---------------- final scalars ----------------
__global__ __launch_bounds__(256) void finals_kernel(
    const float* __restrict__ nll_b, const float* __restrict__ ce_part,
    const float* __restrict__ l2_part, int nparts, float* __restrict__ out4) {
  __shared__ float red[4];
  const int t = threadIdx.x;
  const float snll = block_reduce_sum(nll_b[t] + nll_b[t + 256], red);
  float ce = 0.f;
  #pragma unroll
  for (int i = 0; i < 32; ++i) ce += ce_part[i * 256 + t];
  const float sce = block_reduce_sum(ce, red);
  const float sl2 = block_reduce_sum((t < nparts) ? l2_part[t] : 0.f, red);
  if (t == 0) {
    const float nll = snll / (float)Bsz;
    const float marg = -sce / (float)Bsz;
    const float l2v = WDf * sl2;
    out4[0] = nll;
    out4[1] = marg;
    out4[2] = l2v;
    out4[3] = l2v + nll;
  }
}

// ---------------- launch ----------------
extern "C" void kernel_launch(void* const* d_in, const int* in_sizes, int n_in,
                              void* d_out, int out_size, void* d_ws, size_t ws_size,
                              hipStream_t stream) {
  const float* X = (const float*)d_in[0];
  const float* Y = (const float*)d_in[1];
  const float* noise = (const float*)d_in[2];
  const float* W1 = (const float*)d_in[3];
  const float* b1 = (const float*)d_in[4];
  const float* W2 = (const float*)d_in[5];
  const float* b2 = (const float*)d_in[6];
  const float* W3 = (const float*)d_in[7];
  const float* b3 = (const float*)d_in[8];
  const float* Wmu = (const float*)d_in[9];
  const float* bmu = (const float*)d_in[10];
  const float* rss = (const float*)d_in[11];

  float* ws = (float*)d_ws;
  float* h1 = ws;                         // 512*128
  float* h2 = h1 + 65536;                 // 512*256
  float* feat = h2 + 131072;              // 512*256   (ends 327680)
  float* B0 = ws + 327680;
  float* sqrtcov = B0;                    // 512
  unsigned* rsPu = (unsigned*)(sqrtcov + 512);   // 512*512 fragment-ordered (rs + LSB sign)
  float* ce_part = (float*)(rsPu + 262144);      // 16*512
  float* nll_b = ce_part + 8192;          // 512
  float* l2_part = nll_b + 512;           // 128
  float* lp4 = l2_part + 128;             // 4*100*512 = 204800
  short* RbF = (short*)(lp4 + 204800);    // 4096 entries * 8 shorts
  short* nfB = RbF + 32768;               // 100*32*128*8 shorts

  float* out_prob = (float*)d_out;
  float* out4 = out_prob + (size_t)Bsz * Csz;

  prep_kernel<<<dim3(984), 256, 0, stream>>>(noise, nfB, rss, RbF, sqrtcov,
                                             X, W1, b1, h1, W2, W3, Wmu, l2_part,
                                             rsPu);

  gemm32<true><<<dim3(8, 16), 256, 0, stream>>>(h1, W2, b2, h2, 512, 256, 128);
  gemm32<true><<<dim3(8, 16), 256, 0, stream>>>(h2, W3, b3, feat, 512, 256, 256);
  gemm32_mu<<<dim3(16, 16), 256, 0, stream>>>(feat, Wmu, bmu, Y, sqrtcov,
                                              out_prob, rsPu, ce_part, 512, 500, 256);

  logprob_s4<<<dim3(3200), 256, 0, stream>>>(nfB, RbF, rsPu, lp4);
  nll_kernel<<<dim3(8), 256, 0, stream>>>(lp4, nll_b);

  finals_kernel<<<dim3(1), 256, 0, stream>>>(nll_b, ce_part, l2_part, 64, out4);
}

// Round 17
// 72.151 us; speedup vs baseline: 1.0192x; 1.0192x over previous
//
#include <hip/hip_runtime.h>
#include <cstddef>

#define EPS1f 1e-6f
#define WDf   1e-5f

constexpr int Bsz = 512, Csz = 500, Zsz = 64, Ssz = 100;

typedef short bf16x8 __attribute__((ext_vector_type(8)));
typedef float f32x4 __attribute__((ext_vector_type(4)));

__device__ inline short f2bf(float f) {
  union { float f; unsigned u; } v; v.f = f;
  unsigned r = (v.u + 0x7fffu + ((v.u >> 16) & 1u)) >> 16;   // RNE
  return (short)r;
}

__device__ inline float block_reduce_sum(float v, float* red) {
  #pragma unroll
  for (int off = 32; off > 0; off >>= 1) v += __shfl_down(v, off, 64);
  const int lane = threadIdx.x & 63, wid = threadIdx.x >> 6;
  if (lane == 0) red[wid] = v;
  __syncthreads();
  float r = 0.f;
  if (threadIdx.x == 0) {
    const int nw = blockDim.x >> 6;
    for (int i = 0; i < nw; ++i) r += red[i];
  }
  __syncthreads();
  return r;   // valid in thread 0 only
}

// ---------------- 32x32 double-buffered GEMM body ----------------
__device__ __forceinline__ void gemm32_body(
    const float* __restrict__ A, const float* __restrict__ W,
    const float* __restrict__ bias, float* __restrict__ out,
    int M, int N, int K, int bn0, int bm0, float* As_, float* Ws_, bool relu) {
  const int tid = threadIdx.x;
  const int bn = bn0 * 32, bm = bm0 * 32;
  const int sm = tid >> 3, sk4 = (tid & 7) * 4;
  const int sk = tid >> 3, sn4 = (tid & 7) * 4;
  const int tn = tid & 15, tm = tid >> 4;
  #define AS_(b, k, m) As_[(b) * 1152 + (k) * 36 + (m)]
  #define WS_(b, k, n) Ws_[(b) * 1152 + (k) * 36 + (n)]
  auto loadW = [&](int kt, float4& wv) {
    const float* wrow = W + (size_t)(kt + sk) * N;
    const int nn = bn + sn4;
    if (nn + 3 < N) wv = *reinterpret_cast<const float4*>(wrow + nn);
    else {
      wv.x = (nn + 0 < N) ? wrow[nn + 0] : 0.f;
      wv.y = (nn + 1 < N) ? wrow[nn + 1] : 0.f;
      wv.z = (nn + 2 < N) ? wrow[nn + 2] : 0.f;
      wv.w = (nn + 3 < N) ? wrow[nn + 3] : 0.f;
    }
  };
  {
    float4 av = *reinterpret_cast<const float4*>(A + (size_t)(bm + sm) * K + sk4);
    float4 wv; loadW(0, wv);
    AS_(0, sk4 + 0, sm) = av.x; AS_(0, sk4 + 1, sm) = av.y;
    AS_(0, sk4 + 2, sm) = av.z; AS_(0, sk4 + 3, sm) = av.w;
    *reinterpret_cast<float4*>(&WS_(0, sk, sn4)) = wv;
  }
  __syncthreads();
  float acc[2][2] = {};
  int pb = 0;
  for (int kt = 0; kt < K; kt += 32) {
    const bool more = (kt + 32) < K;
    float4 av2, wv2;
    if (more) {
      av2 = *reinterpret_cast<const float4*>(A + (size_t)(bm + sm) * K + kt + 32 + sk4);
      loadW(kt + 32, wv2);
    }
    #pragma unroll
    for (int k = 0; k < 32; ++k) {
      const float2 a = *reinterpret_cast<const float2*>(&AS_(pb, k, tm * 2));
      const float2 w = *reinterpret_cast<const float2*>(&WS_(pb, k, tn * 2));
      acc[0][0] = fmaf(a.x, w.x, acc[0][0]);
      acc[0][1] = fmaf(a.x, w.y, acc[0][1]);
      acc[1][0] = fmaf(a.y, w.x, acc[1][0]);
      acc[1][1] = fmaf(a.y, w.y, acc[1][1]);
    }
    if (more) {
      const int nb = pb ^ 1;
      AS_(nb, sk4 + 0, sm) = av2.x; AS_(nb, sk4 + 1, sm) = av2.y;
      AS_(nb, sk4 + 2, sm) = av2.z; AS_(nb, sk4 + 3, sm) = av2.w;
      *reinterpret_cast<float4*>(&WS_(nb, sk, sn4)) = wv2;
      __syncthreads();
      pb = nb;
    }
  }
  #pragma unroll
  for (int j = 0; j < 2; ++j) {
    const int n = bn + tn * 2 + j;
    if (n >= N) continue;
    const float bv = bias[n];
    #pragma unroll
    for (int i = 0; i < 2; ++i) {
      const int m = bm + tm * 2 + i;
      float v = acc[i][j] + bv;
      if (relu) v = fmaxf(v, 0.f);
      out[(size_t)m * N + n] = v;
    }
  }
  #undef AS_
  #undef WS_
}

// ---------------- PREP: nprep(0-799) | sqrtcov(800-807) | RbF(808-823) | l2(824-887)
// | gemm1(888-951) | padinit(952-983) ----------------
__global__ __launch_bounds__(256) void prep_kernel(
    const float* __restrict__ noise, short* __restrict__ nfB,
    const float* __restrict__ R, short* __restrict__ RbF, float* __restrict__ sqrtcov,
    const float* __restrict__ X, const float* __restrict__ W1,
    const float* __restrict__ b1, float* __restrict__ h1,
    const float* __restrict__ W2, const float* __restrict__ W3,
    const float* __restrict__ Wmu, float* __restrict__ l2_part,
    float* __restrict__ rsP, float* __restrict__ snP) {
  __shared__ float smem[2304 * 2];
  const int blk = blockIdx.x;
  const int tid = threadIdx.x;
  if (blk < 800) {
    // noise -> bf16 MFMA-fragment layout
    const int g = blk * 256 + tid;       // 204800
    const int s = g >> 11;
    const int r = g & 2047;
    const int bt = r >> 6;
    const int ln = r & 63;
    const int cl = ln & 15, grp = ln >> 4;
    const float* src = noise + ((size_t)(s * 512 + bt * 16 + cl) * 64 + grp * 8);
    const float4 a = *reinterpret_cast<const float4*>(src);
    const float4 b = *reinterpret_cast<const float4*>(src + 4);
    const float4 c = *reinterpret_cast<const float4*>(src + 32);
    const float4 d = *reinterpret_cast<const float4*>(src + 36);
    bf16x8* dst = reinterpret_cast<bf16x8*>(nfB);
    const int u = (s * 32 + bt) * 128 + ln;
    dst[u]      = bf16x8{ f2bf(a.x), f2bf(a.y), f2bf(a.z), f2bf(a.w),
                          f2bf(b.x), f2bf(b.y), f2bf(b.z), f2bf(b.w) };
    dst[u + 64] = bf16x8{ f2bf(c.x), f2bf(c.y), f2bf(c.z), f2bf(c.w),
                          f2bf(d.x), f2bf(d.y), f2bf(d.z), f2bf(d.w) };
  } else if (blk < 808) {
    // sqrt(cov_diag): 4 threads per c
    const int idx = (blk - 800) * 256 + tid;   // 0..2047
    const int c = idx >> 2;
    const int zq = (idx & 3) * 16;
    const bool cv = c < Csz;
    const float* src = R + (size_t)c * Zsz + zq;
    float ss = 0.f;
    if (cv) {
      #pragma unroll
      for (int q = 0; q < 4; ++q) {
        const float4 r4 = *reinterpret_cast<const float4*>(src + q * 4);
        ss = fmaf(r4.x, r4.x, ss); ss = fmaf(r4.y, r4.y, ss);
        ss = fmaf(r4.z, r4.z, ss); ss = fmaf(r4.w, r4.w, ss);
      }
    }
    ss += __shfl_xor(ss, 1, 64);
    ss += __shfl_xor(ss, 2, 64);
    if ((idx & 3) == 0 && cv) sqrtcov[c] = sqrtf(1.f + ss);
  } else if (blk < 824) {
    // R -> bf16 MFMA-fragment layout (zero-padded rows >= Csz)
    const int e = (blk - 808) * 256 + tid;     // 0..4095
    const int ct = e >> 7;
    const int f = (e >> 6) & 1;
    const int lane = e & 63;
    const int cl = lane & 15, grp = lane >> 4;
    const int c = ct * 16 + cl;
    bf16x8 out = {0, 0, 0, 0, 0, 0, 0, 0};
    if (c < Csz) {
      const float* src = R + (size_t)c * Zsz + f * 32 + grp * 8;
      const float4 a = *reinterpret_cast<const float4*>(src);
      const float4 b = *reinterpret_cast<const float4*>(src + 4);
      out = bf16x8{ f2bf(a.x), f2bf(a.y), f2bf(a.z), f2bf(a.w),
                    f2bf(b.x), f2bf(b.y), f2bf(b.z), f2bf(b.w) };
    }
    reinterpret_cast<bf16x8*>(RbF)[e] = out;
  } else if (blk < 888) {
    const int bid = blk - 824;
    const int gid = bid * 256 + tid;
    const int stride = 64 * 256;
    float s = 0.f;
    for (int i = gid; i < 65536; i += stride) { float v = W1[i]; s = fmaf(v, v, s); }
    for (int i = gid; i < 32768; i += stride) { float v = W2[i]; s = fmaf(v, v, s); }
    for (int i = gid; i < 65536; i += stride) { float v = W3[i]; s = fmaf(v, v, s); }
    for (int i = gid; i < 128000; i += stride) { float v = Wmu[i]; s = fmaf(v, v, s); }
    const float tot = block_reduce_sum(s, smem);
    if (tid == 0) l2_part[bid] = tot;
  } else if (blk < 952) {
    const int idx = blk - 888;                  // 0..63
    gemm32_body(X, W1, b1, h1, 512, 128, 512, idx & 3, idx >> 2,
                smem, smem + 2304, true);
  } else {
    // pad-init rsP/snP for n in [496,512) (real 496-499 overwritten by gemm_mu later)
    const int g = (blk - 952) * 256 + tid;      // 0..8191
    const int m = g >> 4;
    const int n = 496 + (g & 15);
    const int idx = ((n >> 4) * 32 + (m >> 4)) * 256
                  + (((n >> 2) & 3) * 16 + (m & 15)) * 4 + (n & 3);
    rsP[idx] = 0.f;                 // u = acc*sn + 0; acc=0 (zero R rows) -> u=0 -> E=0.5
    snP[idx] = -0.70710678f;
  }
}

// ---------------- standalone 32x32 GEMM ----------------
template <bool RELU>
__global__ __launch_bounds__(256) void gemm32(
    const float* __restrict__ A, const float* __restrict__ W,
    const float* __restrict__ bias, float* __restrict__ out,
    int M, int N, int K) {
  __shared__ float smem[2304 * 2];
  gemm32_body(A, W, bias, out, M, N, K, blockIdx.x, blockIdx.y,
              smem, smem + 2304, RELU);
}

// ---------------- MU GEMM: -> indiv_prob, CE partials, fragment-ordered rsP/snP ----------------
// snP = sign(2y-1)*(-1/sqrt2);  rsP = rmu*snP  ->  u = fmaf(acc, sn, rs)
__global__ __launch_bounds__(256) void gemm32_mu(
    const float* __restrict__ A, const float* __restrict__ W,
    const float* __restrict__ bias, const float* __restrict__ Y,
    const float* __restrict__ sqrtcov,
    float* __restrict__ out_prob, float* __restrict__ rsP, float* __restrict__ snP,
    float* __restrict__ ce_part, int M, int N, int K) {
  __shared__ float As[2][32][36];
  __shared__ float Ws[2][32][36];
  const int tid = threadIdx.x;
  const int bn = blockIdx.x * 32, bm = blockIdx.y * 32;
  const int sm = tid >> 3, sk4 = (tid & 7) * 4;
  const int sk = tid >> 3, sn4 = (tid & 7) * 4;
  const int tn = tid & 15, tm = tid >> 4;

  auto loadW = [&](int kt, float4& wv) {
    const float* wrow = W + (size_t)(kt + sk) * N;
    const int nn = bn + sn4;
    if (nn + 3 < N) wv = *reinterpret_cast<const float4*>(wrow + nn);
    else {
      wv.x = (nn + 0 < N) ? wrow[nn + 0] : 0.f;
      wv.y = (nn + 1 < N) ? wrow[nn + 1] : 0.f;
      wv.z = (nn + 2 < N) ? wrow[nn + 2] : 0.f;
      wv.w = (nn + 3 < N) ? wrow[nn + 3] : 0.f;
    }
  };
  {
    float4 av = *reinterpret_cast<const float4*>(A + (size_t)(bm + sm) * K + sk4);
    float4 wv; loadW(0, wv);
    As[0][sk4 + 0][sm] = av.x; As[0][sk4 + 1][sm] = av.y;
    As[0][sk4 + 2][sm] = av.z; As[0][sk4 + 3][sm] = av.w;
    *reinterpret_cast<float4*>(&Ws[0][sk][sn4]) = wv;
  }
  __syncthreads();
  float acc[2][2] = {};
  int pb = 0;
  for (int kt = 0; kt < K; kt += 32) {
    const bool more = (kt + 32) < K;
    float4 av2, wv2;
    if (more) {
      av2 = *reinterpret_cast<const float4*>(A + (size_t)(bm + sm) * K + kt + 32 + sk4);
      loadW(kt + 32, wv2);
    }
    #pragma unroll
    for (int k = 0; k < 32; ++k) {
      const float2 a = *reinterpret_cast<const float2*>(&As[pb][k][tm * 2]);
      const float2 w = *reinterpret_cast<const float2*>(&Ws[pb][k][tn * 2]);
      acc[0][0] = fmaf(a.x, w.x, acc[0][0]);
      acc[0][1] = fmaf(a.x, w.y, acc[0][1]);
      acc[1][0] = fmaf(a.y, w.x, acc[1][0]);
      acc[1][1] = fmaf(a.y, w.y, acc[1][1]);
    }
    if (more) {
      const int nb = pb ^ 1;
      As[nb][sk4 + 0][sm] = av2.x; As[nb][sk4 + 1][sm] = av2.y;
      As[nb][sk4 + 2][sm] = av2.z; As[nb][sk4 + 3][sm] = av2.w;
      *reinterpret_cast<float4*>(&Ws[nb][sk][sn4]) = wv2;
      __syncthreads();
      pb = nb;
    }
  }
  float ce2[2] = {0.f, 0.f};
  #pragma unroll
  for (int i = 0; i < 2; ++i) {
    const int m = bm + tm * 2 + i;
    #pragma unroll
    for (int j = 0; j < 2; ++j) {
      const int n = bn + tn * 2 + j;
      if (n < N) {
        const float v = acc[i][j] + bias[n];
        const float sp = __builtin_amdgcn_rcpf(1.f + __expf(-1.70169f * v));
        const float p = fmaf(sp, 1.f - EPS1f, 0.5f * EPS1f);
        const float q = fmaf(1.f - sp, 1.f - EPS1f, 0.5f * EPS1f);
        const float y = Y[(size_t)m * N + n];
        out_prob[(size_t)m * N + n] = p;
        ce2[i] += __logf((y > 0.5f) ? p : q);
        // fragment-ordered: idx = (ct*32+bt)*256 + lane*4 + j
        const int idx = (((n >> 4) * 32 + (m >> 4)) << 8)
                      + ((((n >> 2) & 3) * 16 + (m & 15)) << 2) + (n & 3);
        const float snc = (y > 0.5f) ? -0.70710678f : 0.70710678f;
        snP[idx] = snc;
        rsP[idx] = v * sqrtcov[n] * snc;
      }
    }
  }
  #pragma unroll
  for (int off = 1; off < 16; off <<= 1) {
    ce2[0] += __shfl_xor(ce2[0], off, 64);
    ce2[1] += __shfl_xor(ce2[1], off, 64);
  }
  if (tn == 0) {
    const int m0 = bm + tm * 2;
    ce_part[(size_t)blockIdx.x * Bsz + m0] = ce2[0];
    ce_part[(size_t)blockIdx.x * Bsz + m0 + 1] = ce2[1];
  }
}

// ---------------- HOT: c-inner MFMA + probit log-likelihood, fully unrolled ----------------
// grid = 100 s x 16 btg x 2 chh = 3200 blocks. Full unroll: compiler software-pipelines
// all 32 operand loads across the 8-iter body (L2-latency cover).
__global__ void logprob_s3(
    const short* __restrict__ nfB, const short* __restrict__ RbF,
    const float* __restrict__ rsP, const float* __restrict__ snP,
    float* __restrict__ lp4) {
  const int blk = blockIdx.x;          // chh + 2*btg + 32*s
  const int chh = blk & 1;
  const int btg = (blk >> 1) & 15;
  const int s = blk >> 5;
  const int wid = threadIdx.x >> 6;
  const int lane = threadIdx.x & 63;
  const int bt = btg * 2 + (wid & 1);
  const int chq = chh * 2 + (wid >> 1);   // 0..3, 8 c-tiles each

  const bf16x8* nf = reinterpret_cast<const bf16x8*>(nfB);
  const int nbase = (s * 32 + bt) * 128 + lane;
  const bf16x8 n0 = nf[nbase];               // resident noise frag
  const bf16x8 n1 = nf[nbase + 64];
  const bf16x8* rf = reinterpret_cast<const bf16x8*>(RbF);

  float lpl = 0.f;                           // log2 domain
  #pragma unroll
  for (int t = 0; t < 8; ++t) {
    const int ct = chq * 8 + t;
    const bf16x8 Rf0 = rf[(ct * 2 + 0) * 64 + lane];
    const bf16x8 Rf1 = rf[(ct * 2 + 1) * 64 + lane];
    f32x4 acc = {0.f, 0.f, 0.f, 0.f};
    acc = __builtin_amdgcn_mfma_f32_16x16x32_bf16(Rf0, n0, acc, 0, 0, 0);
    acc = __builtin_amdgcn_mfma_f32_16x16x32_bf16(Rf1, n1, acc, 0, 0, 0);
    const int fb = (ct * 32 + bt) * 256 + lane * 4;
    const float4 rs4 = *reinterpret_cast<const float4*>(rsP + fb);
    const float4 sn4 = *reinterpret_cast<const float4*>(snP + fb);
    // batched 4-wide probit
    float u[4], sc[4], p[4], e[4];
    u[0] = fmaf(acc[0], sn4.x, rs4.x);
    u[1] = fmaf(acc[1], sn4.y, rs4.y);
    u[2] = fmaf(acc[2], sn4.z, rs4.z);
    u[3] = fmaf(acc[3], sn4.w, rs4.w);
    #pragma unroll
    for (int i = 0; i < 4; ++i)
      sc[i] = __builtin_amdgcn_rcpf(fmaf(0.3275911f, fabsf(u[i]), 1.f));
    #pragma unroll
    for (int i = 0; i < 4; ++i) {
      float q = fmaf(0.5307027145f, sc[i], -0.7265760135f);   // halved A&S coeffs
      q = fmaf(q, sc[i], 0.7107068705f);
      q = fmaf(q, sc[i], -0.142248368f);
      q = fmaf(q, sc[i], 0.127414796f);
      p[i] = q * sc[i];                                        // = 0.5*erfc_poly
    }
    #pragma unroll
    for (int i = 0; i < 4; ++i) e[i] = __expf(-u[i] * u[i]);
    #pragma unroll
    for (int i = 0; i < 4; ++i) {
      const float f = p[i] * e[i];                // Phi for u>=0
      const float Phi = (u[i] < 0.f) ? 1.f - f : f;
      lpl += __log2f(fmaf(Phi, 1.f - EPS1f, 0.5f * EPS1f));
    }
  }
  lpl += __shfl_xor(lpl, 16, 64);
  lpl += __shfl_xor(lpl, 32, 64);
  if (lane < 16) {
    // pad c's (500-511, all in chq 3) each contribute exactly -1.0 in log2
    const float fix = (chq == 3) ? 12.0f : 0.f;
    lp4[(size_t)(chq * Ssz + s) * 512 + bt * 16 + lane] =
        (lpl + fix) * 0.69314718055994531f;
  }
}

// ---------------- per-b log-sum-exp over S (4-way s-parallel, 4-chunk fused) ----------------
__global__ __launch_bounds__(256) void nll_kernel(const float* __restrict__ lp4,
                                                  float* __restrict__ nll_b) {
  __shared__ float sm[4][64], sse[4][64];
  const int bl = threadIdx.x & 63;
  const int sc = threadIdx.x >> 6;
  const int b = blockIdx.x * 64 + bl;
  float m = -3.0e38f, se = 0.f;
  for (int s = sc * 25; s < sc * 25 + 25; ++s) {
    const float v = lp4[(size_t)s * 512 + b]
                  + lp4[(size_t)(Ssz + s) * 512 + b]
                  + lp4[(size_t)(2 * Ssz + s) * 512 + b]
                  + lp4[(size_t)(3 * Ssz + s) * 512 + b];
    const float mn = fmaxf(m, v);
    se = se * __expf(m - mn) + __expf(v - mn);
    m = mn;
  }
  sm[sc][bl] = m; sse[sc][bl] = se;
  __syncthreads();
  if (sc == 0) {
    float M = sm[0][bl];
    #pragma unroll
    for (int i = 1; i < 4; ++i) M = fmaxf(M, sm[i][bl]);
    float SE = 0.f;
    #pragma unroll
    for (int i = 0; i < 4; ++i) SE += sse[i][bl] * __expf(sm[i][bl] - M);
    nll_b[b] = -__logf(SE * (1.f / (float)Ssz)) - M;
  }
}

// ---------------- final scalars ----------------
__global__ __launch_bounds__(256) void finals_kernel(
    const float* __restrict__ nll_b, const float* __restrict__ ce_part,
    const float* __restrict__ l2_part, int nparts, float* __restrict__ out4) {
  __shared__ float red[4];
  const int t = threadIdx.x;
  const float snll = block_reduce_sum(nll_b[t] + nll_b[t + 256], red);
  float ce = 0.f;
  #pragma unroll
  for (int i = 0; i < 32; ++i) ce += ce_part[i * 256 + t];
  const float sce = block_reduce_sum(ce, red);
  const float sl2 = block_reduce_sum((t < nparts) ? l2_part[t] : 0.f, red);
  if (t == 0) {
    const float nll = snll / (float)Bsz;
    const float marg = -sce / (float)Bsz;
    const float l2v = WDf * sl2;
    out4[0] = nll;
    out4[1] = marg;
    out4[2] = l2v;
    out4[3] = l2v + nll;
  }
}

// ---------------- launch ----------------
extern "C" void kernel_launch(void* const* d_in, const int* in_sizes, int n_in,
                              void* d_out, int out_size, void* d_ws, size_t ws_size,
                              hipStream_t stream) {
  const float* X = (const float*)d_in[0];
  const float* Y = (const float*)d_in[1];
  const float* noise = (const float*)d_in[2];
  const float* W1 = (const float*)d_in[3];
  const float* b1 = (const float*)d_in[4];
  const float* W2 = (const float*)d_in[5];
  const float* b2 = (const float*)d_in[6];
  const float* W3 = (const float*)d_in[7];
  const float* b3 = (const float*)d_in[8];
  const float* Wmu = (const float*)d_in[9];
  const float* bmu = (const float*)d_in[10];
  const float* rss = (const float*)d_in[11];

  float* ws = (float*)d_ws;
  float* h1 = ws;                         // 512*128
  float* h2 = h1 + 65536;                 // 512*256
  float* feat = h2 + 131072;              // 512*256   (ends 327680)
  float* B0 = ws + 327680;
  float* sqrtcov = B0;                    // 512
  float* rsP = sqrtcov + 512;             // 512*512 fragment-ordered (rmu*snC)
  float* snP = rsP + 262144;              // 512*512 fragment-ordered (snC)
  float* ce_part = snP + 262144;          // 16*512
  float* nll_b = ce_part + 8192;          // 512
  float* l2_part = nll_b + 512;           // 128
  float* lp4 = l2_part + 128;             // 4*100*512 = 204800
  short* RbF = (short*)(lp4 + 204800);    // 4096 entries * 8 shorts
  short* nfB = RbF + 32768;               // 100*32*128*8 shorts

  float* out_prob = (float*)d_out;
  float* out4 = out_prob + (size_t)Bsz * Csz;

  prep_kernel<<<dim3(984), 256, 0, stream>>>(noise, nfB, rss, RbF, sqrtcov,
                                             X, W1, b1, h1, W2, W3, Wmu, l2_part,
                                             rsP, snP);

  gemm32<true><<<dim3(8, 16), 256, 0, stream>>>(h1, W2, b2, h2, 512, 256, 128);
  gemm32<true><<<dim3(8, 16), 256, 0, stream>>>(h2, W3, b3, feat, 512, 256, 256);
  gemm32_mu<<<dim3(16, 16), 256, 0, stream>>>(feat, Wmu, bmu, Y, sqrtcov,
                                              out_prob, rsP, snP, ce_part, 512, 500, 256);

  logprob_s3<<<dim3(3200), 256, 0, stream>>>(nfB, RbF, rsP, snP, lp4);
  nll_kernel<<<dim3(8), 256, 0, stream>>>(lp4, nll_b);

  finals_kernel<<<dim3(1), 256, 0, stream>>>(nll_b, ce_part, l2_part, 64, out4);
}